// Round 10
// baseline (343.359 us; speedup 1.0000x reference)
//
#include <hip/hip_runtime.h>
#include <math.h>

#define DD 256
#define BATCH 4
#define SEQ 8192
#define NEE 2048
#define NCC 512
#define EPSL 1e-5f
#define INV_SQRT_D 0.0625f

typedef __attribute__((ext_vector_type(8))) short short8;
typedef __attribute__((ext_vector_type(4))) float f32x4;

// ---------------- helpers ----------------
__device__ __forceinline__ float4 ld4(const float* p){ return *(const float4*)p; }
__device__ __forceinline__ void st4(float* p, const float4& v){ *(float4*)p = v; }
__device__ __forceinline__ void fma4(float4& a, float s, const float4& b){
  a.x = fmaf(s,b.x,a.x); a.y = fmaf(s,b.y,a.y); a.z = fmaf(s,b.z,a.z); a.w = fmaf(s,b.w,a.w);
}
// branch-free tanh: (e^{2x}-1)/(e^{2x}+1); abs err ~2e-7, valid |x| < 44
__device__ __forceinline__ float tanh_e2(float x){
  float z = __expf(2.f*x);
  return (z - 1.f) * __builtin_amdgcn_rcpf(z + 1.f);
}
// bf16 round-to-nearest-even split helpers
__device__ __forceinline__ ushort f2bf(float x){
  unsigned u = __float_as_uint(x);
  unsigned r = u + 0x7fffu + ((u >> 16) & 1u);
  return (ushort)(r >> 16);
}
__device__ __forceinline__ float bf2f(ushort h){
  return __uint_as_float(((unsigned)h) << 16);
}

// top-4 with jax.lax.top_k tie semantics: larger val first, ties -> lower index
__device__ __forceinline__ bool t4_better(float v1, int i1, float v2, int i2){
  return (v1 > v2) || (v1 == v2 && i1 < i2);
}
__device__ __forceinline__ void t4_init(float* v, int* i){
#pragma unroll
  for (int k=0;k<4;k++){ v[k] = -INFINITY; i[k] = 0x7fffffff; }
}
__device__ __forceinline__ void t4_insert(float* v, int* i, float nv, int ni){
  if (t4_better(nv, ni, v[3], i[3])){
    v[3]=nv; i[3]=ni;
    if (t4_better(v[3],i[3],v[2],i[2])){ float tv=v[2]; v[2]=v[3]; v[3]=tv; int ti=i[2]; i[2]=i[3]; i[3]=ti;
      if (t4_better(v[2],i[2],v[1],i[1])){ tv=v[1]; v[1]=v[2]; v[2]=tv; ti=i[1]; i[1]=i[2]; i[2]=ti;
        if (t4_better(v[1],i[1],v[0],i[0])){ tv=v[0]; v[0]=v[1]; v[1]=tv; ti=i[0]; i[0]=i[1]; i[1]=ti; }
      }
    }
  }
}
__device__ __forceinline__ void t4_ce(float* v, int* i, int x, int y){
  if (t4_better(v[y],i[y],v[x],i[x])){ float tv=v[x]; v[x]=v[y]; v[y]=tv; int ti=i[x]; i[x]=i[y]; i[y]=ti; }
}
// merge two sorted-desc top4 lists (bitonic): result sorted desc in a
__device__ __forceinline__ void t4_merge(float* av, int* ai, const float* bv, const int* bi){
  float lv[4]; int li[4];
#pragma unroll
  for (int k=0;k<4;k++){
    if (t4_better(av[k],ai[k],bv[3-k],bi[3-k])){ lv[k]=av[k]; li[k]=ai[k]; }
    else { lv[k]=bv[3-k]; li[k]=bi[3-k]; }
  }
  t4_ce(lv,li,0,2); t4_ce(lv,li,1,3); t4_ce(lv,li,0,1); t4_ce(lv,li,2,3);
#pragma unroll
  for (int k=0;k<4;k++){ av[k]=lv[k]; ai[k]=li[k]; }
}
__device__ __forceinline__ void t4_wave_merge(float* v, int* i){
#pragma unroll
  for (int off=1; off<64; off<<=1){
    float bv[4]; int bi[4];
#pragma unroll
    for (int k=0;k<4;k++){ bv[k]=__shfl_xor(v[k],off); bi[k]=__shfl_xor(i[k],off); }
    t4_merge(v,i,bv,bi);
  }
}

// ---------------- K0: degenerate e-chain + global top4 of biases ----------------
__global__ __launch_bounds__(1024) void k0_prep(
    const float* __restrict__ b_expand, const float* __restrict__ b_b2s, const float* __restrict__ b_comp,
    const float* __restrict__ ln_b_c, const float* __restrict__ ln_g_e, const float* __restrict__ ln_b_e,
    float* __restrict__ sumE, int* __restrict__ idxB2S, float* __restrict__ wgtB2S,
    int* __restrict__ idxComp, float* __restrict__ wgtComp)
{
  __shared__ float wv_v[16][4];
  __shared__ int   wv_i[16][4];
  __shared__ int s_idx[3][4];
  __shared__ float s_wgt[3][4];
  __shared__ float red[16];
  int t = threadIdx.x, wv = t>>6, lane = t&63;
  // ---- phase 1: parallel top-4 scans ----
  {
    const float* arr; int n, base_wv, nw;
    if (wv < 2){ arr = b_expand; n = NEE; base_wv = 0;  nw = 2; }
    else if (wv < 14){ arr = b_b2s; n = SEQ; base_wv = 2; nw = 12; }
    else { arr = b_comp; n = NCC; base_wv = 14; nw = 2; }
    int gl = ((wv - base_wv)<<6) + lane;
    int stride = nw<<6;
    float v[4]; int ix[4]; t4_init(v,ix);
    for (int m=gl; m<n; m+=stride) t4_insert(v,ix, arr[m], m);
    t4_wave_merge(v,ix);
    if (lane==0){
#pragma unroll
      for (int k=0;k<4;k++){ wv_v[wv][k]=v[k]; wv_i[wv][k]=ix[k]; }
    }
  }
  __syncthreads();
  // ---- phase 2: per-array merge + softmax (3 threads) ----
  if (t < 3){
    int b0 = (t==0)? 0 : (t==1? 2 : 14);
    int nwv = (t==0)? 2 : (t==1? 12 : 2);
    float v[4]; int ix[4]; t4_init(v,ix);
    for (int wq=b0; wq<b0+nwv; wq++)
#pragma unroll
      for (int k=0;k<4;k++) t4_insert(v,ix, wv_v[wq][k], wv_i[wq][k]);
    float e0=1.f, e1=expf(v[1]-v[0]), e2=expf(v[2]-v[0]), e3=expf(v[3]-v[0]);
    float inv = 1.f/(e0+e1+e2+e3);
    s_idx[t][0]=ix[0]; s_idx[t][1]=ix[1]; s_idx[t][2]=ix[2]; s_idx[t][3]=ix[3];
    s_wgt[t][0]=e0*inv; s_wgt[t][1]=e1*inv; s_wgt[t][2]=e2*inv; s_wgt[t][3]=e3*inv;
  }
  __syncthreads();
  // ---- phase 3: e-chain (threads 0..255; others idle but join barriers) ----
  float c = (t < 256) ? ln_b_c[t] : 0.f;
  float cs = c, cq = c*c;
#pragma unroll
  for (int off=32; off; off>>=1){ cs += __shfl_xor(cs,off); cq += __shfl_xor(cq,off); }
  if (lane==0 && wv<4){ red[wv]=cs; red[8+wv]=cq; }
  __syncthreads();
  if (t < 256){
    float mean_c = (red[0]+red[1]+red[2]+red[3]) * (1.f/256.f);
    float var_c  = (red[8]+red[9]+red[10]+red[11]) * (1.f/256.f) - mean_c*mean_c;
    float cm = c - mean_c;
    float g = ln_g_e[t], be = ln_b_e[t];
    float a[4]; float q = 0.f;
#pragma unroll
    for (int k=0;k<4;k++){
      a[k] = 0.2f * (float)NCC * s_wgt[0][k];   // e_val[idxE_k] = a_k * ln_b_c
      if (s_idx[0][k] < 4) q += a[k];           // dv = mean(e_val[0..3])
    }
    q *= 0.25f;
    float se = 0.f;
#pragma unroll
    for (int k=0;k<4;k++){
      float tk = a[k] + 0.2f*q;
      se += tk*cm*rsqrtf(tk*tk*var_c + EPSL)*g + be;
    }
    float tz = 0.2f*q;
    se += (float)(NEE-4) * (tz*cm*rsqrtf(tz*tz*var_c + EPSL)*g + be);
    sumE[t] = se;
    if (t < 4){
      idxB2S[t] = s_idx[1][t]; wgtB2S[t] = s_wgt[1][t];
      idxComp[t] = s_idx[2][t]; wgtComp[t] = s_wgt[2][t];
    }
  }
}

// ---------------- KZ: fused init -- zero counts, zero ncs, preload ncv with base ----------------
__global__ __launch_bounds__(256) void kz_init(int* __restrict__ counts,
    float* __restrict__ ncs, float* __restrict__ ncv,
    const float* __restrict__ ln_b_c, const float* __restrict__ sumE,
    const int* __restrict__ idxComp, const float* __restrict__ wgtComp)
{
  int bid = blockIdx.x;
  int t = threadIdx.x;
  if (bid < BATCH*NCC){
    int dest = bid & (NCC-1);
    float base = ln_b_c[t];
#pragma unroll
    for (int k=0;k<4;k++) if (dest == idxComp[k]) base = fmaf(0.2f*wgtComp[k], sumE[t], base);
    ncs[((size_t)bid<<8) + t] = 0.f;
    ncv[((size_t)bid<<8) + t] = base;
  } else {
    int i = (bid - BATCH*NCC)*256 + t;
    if (i < BATCH*NCC) counts[i] = 0;
  }
}

// ---------------- K1: window prop + tanh(tanh()) + LN(LN()+b2s rows) ----------------
__global__ __launch_bounds__(256) void k1_window(
    const float* __restrict__ s_state, const float* __restrict__ s_val,
    const float* __restrict__ w_pair_s, const float* __restrict__ ln_g_s, const float* __restrict__ ln_b_s,
    const float* __restrict__ sumE, const int* __restrict__ idxB2S, const float* __restrict__ wgtB2S,
    float* __restrict__ out_state, float* __restrict__ out_val)
{
  int gw = (blockIdx.x << 2) + (threadIdx.x >> 6);
  int lane = threadIdx.x & 63;
  int b = gw >> 13, r = gw & (SEQ-1);
  size_t rowoff = ((size_t)gw) << 8;
  size_t bbase = ((size_t)b) << 21;
  int d0 = lane << 2;
  float4 x = ld4(s_state + rowoff + d0);
  float4 v = ld4(s_val + rowoff + d0);
  float4 wp = ld4(w_pair_s + d0);
  float qx=x.x*wp.x, qy=x.y*wp.y, qz=x.z*wp.z, qw=x.w*wp.w;
  float sc[9]; float4 ns[9];
#pragma unroll
  for (int k=0;k<9;k++){
    int rr = r + k - 4;
    int rc = rr < 0 ? 0 : (rr > SEQ-1 ? SEQ-1 : rr);
    ns[k] = ld4(s_state + bbase + (((size_t)rc)<<8) + d0);
    sc[k] = qx*ns[k].x + qy*ns[k].y + qz*ns[k].z + qw*ns[k].w;
  }
#pragma unroll
  for (int off=32; off; off>>=1){
#pragma unroll
    for (int k=0;k<9;k++) sc[k] += __shfl_xor(sc[k], off);
  }
  float mx = -INFINITY;
#pragma unroll
  for (int k=0;k<9;k++){
    int rr = r + k - 4;
    sc[k] = (rr>=0 && rr<SEQ) ? sc[k]*INV_SQRT_D : -1e30f;
    mx = fmaxf(mx, sc[k]);
  }
  float ssum = 0.f;
#pragma unroll
  for (int k=0;k<9;k++){ sc[k] = __expf(sc[k]-mx); ssum += sc[k]; }
  float inv = __builtin_amdgcn_rcpf(ssum);
  float4 ds = make_float4(0,0,0,0), dv = make_float4(0,0,0,0);
#pragma unroll
  for (int k=0;k<9;k++) fma4(ds, sc[k]*inv, ns[k]);
#pragma unroll
  for (int k=0;k<9;k++){
    int rr = r + k - 4;
    int rc = rr < 0 ? 0 : (rr > SEQ-1 ? SEQ-1 : rr);
    float4 nv = ld4(s_val + bbase + (((size_t)rc)<<8) + d0);
    fma4(dv, sc[k]*inv, nv);
  }
  // state: tanh twice (step1 then step5 with ds==0)
  float4 s1, s2;
  s1.x = tanh_e2(x.x + 0.25f*ds.x); s1.y = tanh_e2(x.y + 0.25f*ds.y);
  s1.z = tanh_e2(x.z + 0.25f*ds.z); s1.w = tanh_e2(x.w + 0.25f*ds.w);
  s2.x = tanh_e2(s1.x); s2.y = tanh_e2(s1.y); s2.z = tanh_e2(s1.z); s2.w = tanh_e2(s1.w);
  st4(out_state + rowoff + d0, s2);
  // val: LN, +sparse rows, LN again
  float4 y;
  y.x = v.x + 0.25f*dv.x; y.y = v.y + 0.25f*dv.y; y.z = v.z + 0.25f*dv.z; y.w = v.w + 0.25f*dv.w;
  float sm = y.x+y.y+y.z+y.w;
  float sq = y.x*y.x+y.y*y.y+y.z*y.z+y.w*y.w;
#pragma unroll
  for (int off=32; off; off>>=1){ sm += __shfl_xor(sm,off); sq += __shfl_xor(sq,off); }
  float mean = sm*(1.f/256.f);
  float rstd = rsqrtf(sq*(1.f/256.f) - mean*mean + EPSL);
  float4 g = ld4(ln_g_s + d0), be = ld4(ln_b_s + d0);
  float4 y1;
  y1.x = (y.x-mean)*rstd*g.x + be.x; y1.y = (y.y-mean)*rstd*g.y + be.y;
  y1.z = (y.z-mean)*rstd*g.z + be.z; y1.w = (y.w-mean)*rstd*g.w + be.w;
#pragma unroll
  for (int k=0;k<4;k++){
    if (r == idxB2S[k]){
      float cb = 0.075f * wgtB2S[k];
      float4 sE = ld4(sumE + d0);
      fma4(y1, cb, sE);
    }
  }
  sm = y1.x+y1.y+y1.z+y1.w;
  sq = y1.x*y1.x+y1.y*y1.y+y1.z*y1.z+y1.w*y1.w;
#pragma unroll
  for (int off=32; off; off>>=1){ sm += __shfl_xor(sm,off); sq += __shfl_xor(sq,off); }
  float mean2 = sm*(1.f/256.f);
  float rstd2 = rsqrtf(sq*(1.f/256.f) - mean2*mean2 + EPSL);
  float4 o;
  o.x = (y1.x-mean2)*rstd2*g.x + be.x; o.y = (y1.y-mean2)*rstd2*g.y + be.y;
  o.z = (y1.z-mean2)*rstd2*g.z + be.z; o.w = (y1.w-mean2)*rstd2*g.w + be.w;
  st4(out_val + rowoff + d0, o);
}

// ---------------- K2w: pack W_s2b into bf16 hi/lo MFMA B-fragment order ----------------
__global__ __launch_bounds__(256) void k2w_pack(const float* __restrict__ W,
    ushort* __restrict__ Whi, ushort* __restrict__ Wlo)
{
  int t = blockIdx.x*256 + threadIdx.x;   // 0..16383
  int kb = t >> 11;
  int cf = (t >> 6) & 31;
  int l  = t & 63;
  int k0 = kb*32 + ((l>>4)<<3);
  int col = (cf<<4) + (l&15);
  size_t off = (size_t)t << 3;
#pragma unroll
  for (int j=0;j<8;j++){
    float x = W[(size_t)(k0+j)*NCC + col];
    ushort h = f2bf(x);
    Whi[off+j] = h;
    Wlo[off+j] = f2bf(x - bf2f(h));
  }
}

// ---------------- K2: split-bf16 MFMA GEMM (32768x512x256) + per-row top4 ----------------
// 64 rows x 512 cols per block (512 blocks, 2/CU): halves per-CU W-from-L2
// traffic vs 32-row blocks and doubles MFMA per load-group (24/phase), so the
// pipeline's load latency is covered by twice the compute. acc[4][8] lives in
// AGPRs (unified file); __launch_bounds__(256,2) = 256 reg/wave budget.
__global__ __launch_bounds__(256, 2) void k2_mfma(
    const float* __restrict__ A, const ushort* __restrict__ Whi,
    const float* __restrict__ bias,
    int* __restrict__ topk_idx, float* __restrict__ topk_wgt, int* __restrict__ counts)
{
  __shared__ __align__(16) ushort Asp[2][64][264];   // [hi/lo][row][k], pad 264 -> 528B stride
  __shared__ float mv[64][17];                        // [row][w*4+r], stride 17 = conflict-free
  __shared__ int   mi[64][17];
  int tid = threadIdx.x;
  size_t row_base = (size_t)blockIdx.x * 64;
  int w = tid >> 6, l = tid & 63;
  int lg = l >> 4, lr = l & 15;
  // per-lane W base (shorts): w*4096 + l*8; lo plane at +131072 shorts
  const ushort* pw = Whi + ((w<<12) + (l<<3));

#define LOADG(KB, G, DST) { \
    const ushort* _p = pw + (KB)*16384 + (G)*1024; \
    DST[0] = *(const short8*)_p; \
    DST[2] = *(const short8*)(_p + 512); \
    DST[1] = *(const short8*)(_p + 131072); \
    DST[3] = *(const short8*)(_p + 131072 + 512); }

// 24 MFMA per phase: B[0]=hi(c0) B[2]=hi(c1) B[1]=lo(c0) B[3]=lo(c1)
#define COMPG(G, B) { \
    int _c0 = (G)<<1, _c1 = _c0+1; \
    acc[0][_c0] = __builtin_amdgcn_mfma_f32_16x16x32_bf16(ah[0], B[0], acc[0][_c0], 0,0,0); \
    acc[1][_c0] = __builtin_amdgcn_mfma_f32_16x16x32_bf16(ah[1], B[0], acc[1][_c0], 0,0,0); \
    acc[2][_c0] = __builtin_amdgcn_mfma_f32_16x16x32_bf16(ah[2], B[0], acc[2][_c0], 0,0,0); \
    acc[3][_c0] = __builtin_amdgcn_mfma_f32_16x16x32_bf16(ah[3], B[0], acc[3][_c0], 0,0,0); \
    acc[0][_c1] = __builtin_amdgcn_mfma_f32_16x16x32_bf16(ah[0], B[2], acc[0][_c1], 0,0,0); \
    acc[1][_c1] = __builtin_amdgcn_mfma_f32_16x16x32_bf16(ah[1], B[2], acc[1][_c1], 0,0,0); \
    acc[2][_c1] = __builtin_amdgcn_mfma_f32_16x16x32_bf16(ah[2], B[2], acc[2][_c1], 0,0,0); \
    acc[3][_c1] = __builtin_amdgcn_mfma_f32_16x16x32_bf16(ah[3], B[2], acc[3][_c1], 0,0,0); \
    acc[0][_c0] = __builtin_amdgcn_mfma_f32_16x16x32_bf16(al[0], B[0], acc[0][_c0], 0,0,0); \
    acc[1][_c0] = __builtin_amdgcn_mfma_f32_16x16x32_bf16(al[1], B[0], acc[1][_c0], 0,0,0); \
    acc[2][_c0] = __builtin_amdgcn_mfma_f32_16x16x32_bf16(al[2], B[0], acc[2][_c0], 0,0,0); \
    acc[3][_c0] = __builtin_amdgcn_mfma_f32_16x16x32_bf16(al[3], B[0], acc[3][_c0], 0,0,0); \
    acc[0][_c1] = __builtin_amdgcn_mfma_f32_16x16x32_bf16(al[0], B[2], acc[0][_c1], 0,0,0); \
    acc[1][_c1] = __builtin_amdgcn_mfma_f32_16x16x32_bf16(al[1], B[2], acc[1][_c1], 0,0,0); \
    acc[2][_c1] = __builtin_amdgcn_mfma_f32_16x16x32_bf16(al[2], B[2], acc[2][_c1], 0,0,0); \
    acc[3][_c1] = __builtin_amdgcn_mfma_f32_16x16x32_bf16(al[3], B[2], acc[3][_c1], 0,0,0); \
    acc[0][_c0] = __builtin_amdgcn_mfma_f32_16x16x32_bf16(ah[0], B[1], acc[0][_c0], 0,0,0); \
    acc[1][_c0] = __builtin_amdgcn_mfma_f32_16x16x32_bf16(ah[1], B[1], acc[1][_c0], 0,0,0); \
    acc[2][_c0] = __builtin_amdgcn_mfma_f32_16x16x32_bf16(ah[2], B[1], acc[2][_c0], 0,0,0); \
    acc[3][_c0] = __builtin_amdgcn_mfma_f32_16x16x32_bf16(ah[3], B[1], acc[3][_c0], 0,0,0); \
    acc[0][_c1] = __builtin_amdgcn_mfma_f32_16x16x32_bf16(ah[0], B[3], acc[0][_c1], 0,0,0); \
    acc[1][_c1] = __builtin_amdgcn_mfma_f32_16x16x32_bf16(ah[1], B[3], acc[1][_c1], 0,0,0); \
    acc[2][_c1] = __builtin_amdgcn_mfma_f32_16x16x32_bf16(ah[2], B[3], acc[2][_c1], 0,0,0); \
    acc[3][_c1] = __builtin_amdgcn_mfma_f32_16x16x32_bf16(ah[3], B[3], acc[3][_c1], 0,0,0); }

  // prologue: first B group in flight before the A-stage barrier
  short8 bA[4], bB[4];
  LOADG(0, 0, bA);
  // ---- stage + split A (fp32 -> bf16 hi/lo): 64 rows ----
  {
    const float4* Ab = (const float4*)(A + row_base*DD);
#pragma unroll
    for (int i=0;i<16;i++){
      int q = i*256 + tid;           // 0..4095 = 64 rows x 64 float4
      int row = q >> 6, k4 = q & 63;
      float4 x = Ab[q];
      ushort4 h, lo;
      h.x = f2bf(x.x); h.y = f2bf(x.y); h.z = f2bf(x.z); h.w = f2bf(x.w);
      lo.x = f2bf(x.x - bf2f(h.x)); lo.y = f2bf(x.y - bf2f(h.y));
      lo.z = f2bf(x.z - bf2f(h.z)); lo.w = f2bf(x.w - bf2f(h.w));
      *(ushort4*)&Asp[0][row][k4*4] = h;
      *(ushort4*)&Asp[1][row][k4*4] = lo;
    }
  }
  __syncthreads();
  f32x4 acc[4][8];
#pragma unroll
  for (int rf=0; rf<4; rf++)
#pragma unroll
    for (int cf=0; cf<8; cf++) acc[rf][cf] = (f32x4){0.f,0.f,0.f,0.f};
#pragma unroll 1
  for (int kb=0; kb<8; kb++){
    int ka = kb*32 + (lg<<3);
    short8 ah[4], al[4];
#pragma unroll
    for (int rf=0; rf<4; rf++){
      int row = (rf<<4) + lr;
      ah[rf] = *(const short8*)&Asp[0][row][ka];
      al[rf] = *(const short8*)&Asp[1][row][ka];
    }
    LOADG(kb, 1, bB);
    __builtin_amdgcn_sched_barrier(0);
    COMPG(0, bA);
    LOADG(kb, 2, bA);
    __builtin_amdgcn_sched_barrier(0);
    COMPG(1, bB);
    LOADG(kb, 3, bB);
    __builtin_amdgcn_sched_barrier(0);
    COMPG(2, bA);
    if (kb < 7) LOADG(kb+1, 0, bA);
    __builtin_amdgcn_sched_barrier(0);
    COMPG(3, bB);
  }
#undef LOADG
#undef COMPG
  // ---- per-row top4 via 4 max-reduction rounds ----
  // D mapping: col = (w<<7)+(cf<<4)+lr, row = (rf<<4)+(lg<<2)+reg
  float bcol[8];
  int rel[8];
#pragma unroll
  for (int cf=0; cf<8; cf++){
    bcol[cf] = bias[(w<<7) + (cf<<4) + lr];
    rel[cf] = (cf<<4) + lr;
  }
#pragma unroll
  for (int rf=0; rf<4; rf++){
#pragma unroll
    for (int reg=0; reg<4; reg++){
      float av[8];
#pragma unroll
      for (int cf=0; cf<8; cf++) av[cf] = acc[rf][cf][reg] + bcol[cf];
      float tv4[4]; int tc4[4];
#pragma unroll
      for (int r=0; r<4; r++){
        float m = fmaxf(fmaxf(fmaxf(av[0],av[1]),fmaxf(av[2],av[3])),
                        fmaxf(fmaxf(av[4],av[5]),fmaxf(av[6],av[7])));
#pragma unroll
        for (int off=1; off<16; off<<=1) m = fmaxf(m, __shfl_xor(m, off));
        int cand = 0x7fffffff;
#pragma unroll
        for (int cf=7; cf>=0; cf--) cand = (av[cf]==m) ? rel[cf] : cand;  // lowest matching col in lane
#pragma unroll
        for (int off=1; off<16; off<<=1) cand = min(cand, __shfl_xor(cand, off));
        tv4[r] = m; tc4[r] = cand;
        if (r < 3){
#pragma unroll
          for (int cf=0; cf<8; cf++) av[cf] = (rel[cf]==cand) ? -INFINITY : av[cf];
        }
      }
      if (lr == 0){
        int rowl = (rf<<4) + (lg<<2) + reg;
#pragma unroll
        for (int r=0; r<4; r++){ mv[rowl][(w<<2)+r] = tv4[r]; mi[rowl][(w<<2)+r] = (w<<7) + tc4[r]; }
      }
    }
  }
  __syncthreads();
  if (tid < 64){
    float v[4]; int ix[4]; t4_init(v, ix);
#pragma unroll
    for (int j=0; j<16; j++) t4_insert(v, ix, mv[tid][j], mi[tid][j]);
    float e0=1.f, e1=expf(v[1]-v[0]), e2=expf(v[2]-v[0]), e3=expf(v[3]-v[0]);
    float inv = 1.f/(e0+e1+e2+e3);
    size_t row = row_base + tid;
    int b = (int)(row >> 13);
    topk_idx[row*4+0]=ix[0]; topk_idx[row*4+1]=ix[1]; topk_idx[row*4+2]=ix[2]; topk_idx[row*4+3]=ix[3];
    topk_wgt[row*4+0]=e0*inv; topk_wgt[row*4+1]=e1*inv; topk_wgt[row*4+2]=e2*inv; topk_wgt[row*4+3]=e3*inv;
    atomicAdd(&counts[(b<<9)+ix[0]],1); atomicAdd(&counts[(b<<9)+ix[1]],1);
    atomicAdd(&counts[(b<<9)+ix[2]],1); atomicAdd(&counts[(b<<9)+ix[3]],1);
  }
}

__global__ __launch_bounds__(256) void k3_scan(const int* __restrict__ counts,
    int* __restrict__ offsets, int* __restrict__ cursor)
{
  __shared__ int part[256];
  int t = threadIdx.x;
  int loc[8]; int s = 0;
#pragma unroll
  for (int i=0;i<8;i++){ loc[i] = counts[t*8+i]; s += loc[i]; }
  part[t] = s;
  __syncthreads();
  for (int off=1; off<256; off<<=1){
    int add = (t>=off)? part[t-off] : 0;
    __syncthreads();
    part[t] += add;
    __syncthreads();
  }
  int run = part[t] - s;
#pragma unroll
  for (int i=0;i<8;i++){ offsets[t*8+i] = run; cursor[t*8+i] = run; run += loc[i]; }
  if (t==255) offsets[BATCH*NCC] = run;
}

__global__ void k4_fill(const int* __restrict__ topk_idx, const float* __restrict__ topk_wgt,
    int* __restrict__ cursor, int* __restrict__ csr_src, float* __restrict__ csr_wgt)
{
  int row = blockIdx.x*256 + threadIdx.x;
  if (row >= BATCH*SEQ) return;
  int b = row >> 13, r = row & (SEQ-1);
#pragma unroll
  for (int k=0;k<4;k++){
    int dest = topk_idx[row*4+k];
    float wgt = topk_wgt[row*4+k];
    int pos = atomicAdd(&cursor[(b<<9)+dest], 1);
    csr_src[pos] = r;
    csr_wgt[pos] = 0.075f * wgt;   // fold sc_sb = ALPHA*BS2B*X_SC
  }
}

// ---------------- K5: per-destination gather-accumulate ----------------
__global__ __launch_bounds__(256) void k5_gather(
    const int* __restrict__ offsets, const int* __restrict__ csr_src, const float* __restrict__ csr_wgt,
    const float* __restrict__ st, const float* __restrict__ vl,
    float* __restrict__ ncs, float* __restrict__ ncv)
{
  int g2 = blockIdx.x;              // 0..4095
  int g  = g2 >> 1;                 // (b,dest)
  int half = g2 & 1;
  int b = g >> 9;
  int t = threadIdx.x;
  int i0 = offsets[g], i1 = offsets[g+1];
  int n = i1 - i0;
  int ia = i0 + ((n * half) >> 1);
  int ib = i0 + ((n * (half+1)) >> 1);
  if (ia >= ib) return;
  const float* Sb = st + (((size_t)b)<<21);
  const float* Vb = vl + (((size_t)b)<<21);
  float as0=0.f, as1=0.f, as2=0.f, as3=0.f;
  float av0=0.f, av1=0.f, av2=0.f, av3=0.f;
  int i = ia;
  for (; i+3 < ib; i += 4){
    int s0 = csr_src[i],   s1 = csr_src[i+1], s2 = csr_src[i+2], s3 = csr_src[i+3];
    float w0 = csr_wgt[i], w1 = csr_wgt[i+1], w2 = csr_wgt[i+2], w3 = csr_wgt[i+3];
    float x0 = Sb[((size_t)s0<<8)+t], y0 = Vb[((size_t)s0<<8)+t];
    float x1 = Sb[((size_t)s1<<8)+t], y1 = Vb[((size_t)s1<<8)+t];
    float x2 = Sb[((size_t)s2<<8)+t], y2 = Vb[((size_t)s2<<8)+t];
    float x3 = Sb[((size_t)s3<<8)+t], y3 = Vb[((size_t)s3<<8)+t];
    as0 = fmaf(w0,x0,as0); av0 = fmaf(w0,y0,av0);
    as1 = fmaf(w1,x1,as1); av1 = fmaf(w1,y1,av1);
    as2 = fmaf(w2,x2,as2); av2 = fmaf(w2,y2,av2);
    as3 = fmaf(w3,x3,as3); av3 = fmaf(w3,y3,av3);
  }
  for (; i < ib; i++){
    int src = csr_src[i];
    float wg = csr_wgt[i];
    as0 = fmaf(wg, Sb[((size_t)src<<8)+t], as0);
    av0 = fmaf(wg, Vb[((size_t)src<<8)+t], av0);
  }
  float accs = (as0+as1)+(as2+as3);
  float accv = (av0+av1)+(av2+av3);
  atomicAdd(&ncs[((size_t)g<<8) + t], accs);
  atomicAdd(&ncv[((size_t)g<<8) + t], accv);
}

// transpose nc_state (per batch 512x256 -> 256x512) for the score GEMM
__global__ __launch_bounds__(256) void k5t_transpose(const float* __restrict__ ncs, float* __restrict__ ncsT){
  __shared__ float tile[64][65];
  int b = blockIdx.z;
  int m0 = blockIdx.x*64, d0 = blockIdx.y*64;
  int tx = threadIdx.x & 63, ty = threadIdx.x >> 6;
  const float* src = ncs + (((size_t)b)<<17);
  for (int i=ty; i<64; i+=4) tile[i][tx] = src[(size_t)(m0+i)*DD + d0 + tx];
  __syncthreads();
  float* dst = ncsT + (((size_t)b)<<17);
  for (int i=ty; i<64; i+=4) dst[(size_t)(d0+i)*NCC + m0 + tx] = tile[tx][i];
}

// ---------------- K6: nc top-k prop (score GEMM + top4 + tanh/LN) ----------------
// 8 rows/block -> 256 blocks; kk loop staggered per block; fast transcendentals.
__global__ __launch_bounds__(256) void k6_ncprop(
    const float* __restrict__ ncs, const float* __restrict__ ncv, const float* __restrict__ ncsT,
    const float* __restrict__ w_pair_c, const float* __restrict__ ln_g_c, const float* __restrict__ ln_b_c,
    float* __restrict__ o_ncs, float* __restrict__ o_ncv)
{
  __shared__ float Alds[256*13];
  int tid = threadIdx.x;
  int b = blockIdx.x >> 6;
  int n_base = (blockIdx.x & 63) << 3;
  const float* Sb = ncs + (((size_t)b)<<17);
  const float* Vb = ncv + (((size_t)b)<<17);
  const float* Tb = ncsT + (((size_t)b)<<17);
  float wc = w_pair_c[tid] * INV_SQRT_D;
#pragma unroll
  for (int i=0;i<8;i++) Alds[tid*13 + i] = Sb[(size_t)(n_base+i)*DD + tid] * wc;
  __syncthreads();
  int lane = tid & 63, rg = tid >> 6;
  int r0 = rg << 1, c0 = lane << 3;
  float acc[2][8];
#pragma unroll
  for (int j=0;j<2;j++)
#pragma unroll
    for (int c=0;c<8;c++) acc[j][c] = 0.f;
  int kk0 = (blockIdx.x << 2) & 255;
  for (int i=0; i<256; i++){
    int kk = (kk0 + i) & 255;
    float4 w0 = ld4(Tb + (size_t)kk*NCC + c0);
    float4 w1 = ld4(Tb + (size_t)kk*NCC + c0 + 4);
    float a0 = Alds[kk*13 + r0];
    float a1 = Alds[kk*13 + r0 + 1];
    float wv_[8] = {w0.x,w0.y,w0.z,w0.w,w1.x,w1.y,w1.z,w1.w};
#pragma unroll
    for (int c=0;c<8;c++){
      acc[0][c] = fmaf(a0, wv_[c], acc[0][c]);
      acc[1][c] = fmaf(a1, wv_[c], acc[1][c]);
    }
  }
  int d0 = lane << 2;
  float4 g4 = ld4(ln_g_c + d0), be4 = ld4(ln_b_c + d0);
#pragma unroll
  for (int j=0;j<2;j++){
    float tv[4]; int ti[4]; t4_init(tv,ti);
#pragma unroll
    for (int c=0;c<8;c++) t4_insert(tv,ti, acc[j][c], c0+c);
    t4_wave_merge(tv,ti);
    float e0=1.f, e1=__expf(tv[1]-tv[0]), e2=__expf(tv[2]-tv[0]), e3=__expf(tv[3]-tv[0]);
    float inv = __builtin_amdgcn_rcpf(e0+e1+e2+e3);
    float aw[4] = {e0*inv, e1*inv, e2*inv, e3*inv};
    int n = n_base + r0 + j;
    float4 stt = ld4(Sb + (size_t)n*DD + d0);
    float4 vv  = ld4(Vb + (size_t)n*DD + d0);
    float4 dsv = make_float4(0,0,0,0), dvv = make_float4(0,0,0,0);
#pragma unroll
    for (int k=0;k<4;k++){
      float4 ms = ld4(Sb + (size_t)ti[k]*DD + d0);
      float4 mv = ld4(Vb + (size_t)ti[k]*DD + d0);
      fma4(dsv, aw[k], ms); fma4(dvv, aw[k], mv);
    }
    float4 os;
    os.x = tanh_e2(stt.x + 0.2f*dsv.x); os.y = tanh_e2(stt.y + 0.2f*dsv.y);
    os.z = tanh_e2(stt.z + 0.2f*dsv.z); os.w = tanh_e2(stt.w + 0.2f*dsv.w);
    size_t orow = (((size_t)b)<<17) + ((size_t)n<<8);
    st4(o_ncs + orow + d0, os);
    float4 y;
    y.x = vv.x + 0.2f*dvv.x; y.y = vv.y + 0.2f*dvv.y;
    y.z = vv.z + 0.2f*dvv.z; y.w = vv.w + 0.2f*dvv.w;
    float sm = y.x+y.y+y.z+y.w;
    float sq = y.x*y.x+y.y*y.y+y.z*y.z+y.w*y.w;
#pragma unroll
    for (int off=32; off; off>>=1){ sm += __shfl_xor(sm,off); sq += __shfl_xor(sq,off); }
    float mean = sm*(1.f/256.f);
    float rstd = rsqrtf(sq*(1.f/256.f) - mean*mean + EPSL);
    float4 o;
    o.x = (y.x-mean)*rstd*g4.x + be4.x; o.y = (y.y-mean)*rstd*g4.y + be4.y;
    o.z = (y.z-mean)*rstd*g4.z + be4.z; o.w = (y.w-mean)*rstd*g4.w + be4.w;
    st4(o_ncv + orow + d0, o);
  }
}

// ---------------- launch ----------------
extern "C" void kernel_launch(void* const* d_in, const int* in_sizes, int n_in,
                              void* d_out, int out_size, void* d_ws, size_t ws_size,
                              hipStream_t stream)
{
  const float* s_state = (const float*)d_in[0];
  const float* s_val   = (const float*)d_in[1];
  const float* w_pair_s= (const float*)d_in[2];
  const float* w_pair_c= (const float*)d_in[4];
  const float* b_expand= (const float*)d_in[6];
  const float* b_b2s   = (const float*)d_in[8];
  const float* b_comp  = (const float*)d_in[10];
  const float* W_s2b   = (const float*)d_in[11];
  const float* b_s2b   = (const float*)d_in[12];
  const float* ln_g_s  = (const float*)d_in[13];
  const float* ln_b_s  = (const float*)d_in[14];
  const float* ln_g_e  = (const float*)d_in[15];
  const float* ln_b_e  = (const float*)d_in[16];
  const float* ln_g_c  = (const float*)d_in[17];
  const float* ln_b_c  = (const float*)d_in[18];

  float* o_sstate = (float*)d_out;
  float* o_sval   = o_sstate + (size_t)BATCH*SEQ*DD;
  float* o_ncs    = o_sval + (size_t)BATCH*SEQ*DD;
  float* o_ncv    = o_ncs + (size_t)BATCH*NCC*DD;

  char* w = (char*)d_ws;
  float* sumE    = (float*)(w);
  int*   idxB2S  = (int*)(w + 1024);
  float* wgtB2S  = (float*)(w + 1040);
  int*   idxComp = (int*)(w + 1056);
  float* wgtComp = (float*)(w + 1072);
  int*   topk_idx= (int*)(w + 4096);
  float* topk_wgt= (float*)(w + 4096 + 524288);
  int*   counts  = (int*)(w + 1052672);
  int*   offsets = (int*)(w + 1069056);
  int*   cursor  = (int*)(w + 1085440);
  int*   csr_src = (int*)(w + 1101824);
  float* csr_wgt = (float*)(w + 1626112);
  float* ncs_ws  = (float*)(w + 2150400);
  float* ncv_ws  = ncs_ws + (size_t)BATCH*NCC*DD;
  float* ncsT_ws = ncv_ws + (size_t)BATCH*NCC*DD;
  ushort* wpk_hi = (ushort*)(w + 8441856);
  ushort* wpk_lo = (ushort*)(w + 8441856 + 262144);   // contiguous: lo = hi + 131072 shorts

  hipLaunchKernelGGL(k0_prep, dim3(1), dim3(1024), 0, stream,
      b_expand, b_b2s, b_comp, ln_b_c, ln_g_e, ln_b_e, sumE, idxB2S, wgtB2S, idxComp, wgtComp);
  hipLaunchKernelGGL(kz_init, dim3(BATCH*NCC + 8), dim3(256), 0, stream,
      counts, ncs_ws, ncv_ws, ln_b_c, sumE, idxComp, wgtComp);
  hipLaunchKernelGGL(k2w_pack, dim3(64), dim3(256), 0, stream, W_s2b, wpk_hi, wpk_lo);
  hipLaunchKernelGGL(k1_window, dim3(8192), dim3(256), 0, stream,
      s_state, s_val, w_pair_s, ln_g_s, ln_b_s, sumE, idxB2S, wgtB2S, o_sstate, o_sval);
  hipLaunchKernelGGL(k2_mfma, dim3(512), dim3(256), 0, stream,
      o_sstate, wpk_hi, b_s2b, topk_idx, topk_wgt, counts);
  hipLaunchKernelGGL(k3_scan, dim3(1), dim3(256), 0, stream, counts, offsets, cursor);
  hipLaunchKernelGGL(k4_fill, dim3(128), dim3(256), 0, stream,
      topk_idx, topk_wgt, cursor, csr_src, csr_wgt);
  hipLaunchKernelGGL(k5_gather, dim3(4096), dim3(256), 0, stream,
      offsets, csr_src, csr_wgt, o_sstate, o_sval, ncs_ws, ncv_ws);
  hipLaunchKernelGGL(k5t_transpose, dim3(8,4,BATCH), dim3(256), 0, stream, ncs_ws, ncsT_ws);
  hipLaunchKernelGGL(k6_ncprop, dim3(256), dim3(256), 0, stream,
      ncs_ws, ncv_ws, ncsT_ws, w_pair_c, ln_g_c, ln_b_c, o_ncs, o_ncv);
}

// Round 11
// 341.946 us; speedup vs baseline: 1.0041x; 1.0041x over previous
//
#include <hip/hip_runtime.h>
#include <math.h>

#define DD 256
#define BATCH 4
#define SEQ 8192
#define NEE 2048
#define NCC 512
#define EPSL 1e-5f
#define INV_SQRT_D 0.0625f

typedef __attribute__((ext_vector_type(8))) short short8;
typedef __attribute__((ext_vector_type(4))) float f32x4;

// ---------------- helpers ----------------
__device__ __forceinline__ float4 ld4(const float* p){ return *(const float4*)p; }
__device__ __forceinline__ void st4(float* p, const float4& v){ *(float4*)p = v; }
__device__ __forceinline__ void fma4(float4& a, float s, const float4& b){
  a.x = fmaf(s,b.x,a.x); a.y = fmaf(s,b.y,a.y); a.z = fmaf(s,b.z,a.z); a.w = fmaf(s,b.w,a.w);
}
// branch-free tanh: (e^{2x}-1)/(e^{2x}+1); abs err ~2e-7, valid |x| < 44
__device__ __forceinline__ float tanh_e2(float x){
  float z = __expf(2.f*x);
  return (z - 1.f) * __builtin_amdgcn_rcpf(z + 1.f);
}
// bf16 round-to-nearest-even split helpers
__device__ __forceinline__ ushort f2bf(float x){
  unsigned u = __float_as_uint(x);
  unsigned r = u + 0x7fffu + ((u >> 16) & 1u);
  return (ushort)(r >> 16);
}
__device__ __forceinline__ float bf2f(ushort h){
  return __uint_as_float(((unsigned)h) << 16);
}

// top-4 with jax.lax.top_k tie semantics: larger val first, ties -> lower index
__device__ __forceinline__ bool t4_better(float v1, int i1, float v2, int i2){
  return (v1 > v2) || (v1 == v2 && i1 < i2);
}
__device__ __forceinline__ void t4_init(float* v, int* i){
#pragma unroll
  for (int k=0;k<4;k++){ v[k] = -INFINITY; i[k] = 0x7fffffff; }
}
__device__ __forceinline__ void t4_insert(float* v, int* i, float nv, int ni){
  if (t4_better(nv, ni, v[3], i[3])){
    v[3]=nv; i[3]=ni;
    if (t4_better(v[3],i[3],v[2],i[2])){ float tv=v[2]; v[2]=v[3]; v[3]=tv; int ti=i[2]; i[2]=i[3]; i[3]=ti;
      if (t4_better(v[2],i[2],v[1],i[1])){ tv=v[1]; v[1]=v[2]; v[2]=tv; ti=i[1]; i[1]=i[2]; i[2]=ti;
        if (t4_better(v[1],i[1],v[0],i[0])){ tv=v[0]; v[0]=v[1]; v[1]=tv; ti=i[0]; i[0]=i[1]; i[1]=ti; }
      }
    }
  }
}
__device__ __forceinline__ void t4_ce(float* v, int* i, int x, int y){
  if (t4_better(v[y],i[y],v[x],i[x])){ float tv=v[x]; v[x]=v[y]; v[y]=tv; int ti=i[x]; i[x]=i[y]; i[y]=ti; }
}
// merge two sorted-desc top4 lists (bitonic): result sorted desc in a
__device__ __forceinline__ void t4_merge(float* av, int* ai, const float* bv, const int* bi){
  float lv[4]; int li[4];
#pragma unroll
  for (int k=0;k<4;k++){
    if (t4_better(av[k],ai[k],bv[3-k],bi[3-k])){ lv[k]=av[k]; li[k]=ai[k]; }
    else { lv[k]=bv[3-k]; li[k]=bi[3-k]; }
  }
  t4_ce(lv,li,0,2); t4_ce(lv,li,1,3); t4_ce(lv,li,0,1); t4_ce(lv,li,2,3);
#pragma unroll
  for (int k=0;k<4;k++){ av[k]=lv[k]; ai[k]=li[k]; }
}
__device__ __forceinline__ void t4_wave_merge(float* v, int* i){
#pragma unroll
  for (int off=1; off<64; off<<=1){
    float bv[4]; int bi[4];
#pragma unroll
    for (int k=0;k<4;k++){ bv[k]=__shfl_xor(v[k],off); bi[k]=__shfl_xor(i[k],off); }
    t4_merge(v,i,bv,bi);
  }
}

// ---------------- K0: degenerate e-chain + global top4 of biases ----------------
__global__ __launch_bounds__(1024) void k0_prep(
    const float* __restrict__ b_expand, const float* __restrict__ b_b2s, const float* __restrict__ b_comp,
    const float* __restrict__ ln_b_c, const float* __restrict__ ln_g_e, const float* __restrict__ ln_b_e,
    float* __restrict__ sumE, int* __restrict__ idxB2S, float* __restrict__ wgtB2S,
    int* __restrict__ idxComp, float* __restrict__ wgtComp)
{
  __shared__ float wv_v[16][4];
  __shared__ int   wv_i[16][4];
  __shared__ int s_idx[3][4];
  __shared__ float s_wgt[3][4];
  __shared__ float red[16];
  int t = threadIdx.x, wv = t>>6, lane = t&63;
  // ---- phase 1: parallel top-4 scans ----
  {
    const float* arr; int n, base_wv, nw;
    if (wv < 2){ arr = b_expand; n = NEE; base_wv = 0;  nw = 2; }
    else if (wv < 14){ arr = b_b2s; n = SEQ; base_wv = 2; nw = 12; }
    else { arr = b_comp; n = NCC; base_wv = 14; nw = 2; }
    int gl = ((wv - base_wv)<<6) + lane;
    int stride = nw<<6;
    float v[4]; int ix[4]; t4_init(v,ix);
    for (int m=gl; m<n; m+=stride) t4_insert(v,ix, arr[m], m);
    t4_wave_merge(v,ix);
    if (lane==0){
#pragma unroll
      for (int k=0;k<4;k++){ wv_v[wv][k]=v[k]; wv_i[wv][k]=ix[k]; }
    }
  }
  __syncthreads();
  // ---- phase 2: per-array merge + softmax (3 threads) ----
  if (t < 3){
    int b0 = (t==0)? 0 : (t==1? 2 : 14);
    int nwv = (t==0)? 2 : (t==1? 12 : 2);
    float v[4]; int ix[4]; t4_init(v,ix);
    for (int wq=b0; wq<b0+nwv; wq++)
#pragma unroll
      for (int k=0;k<4;k++) t4_insert(v,ix, wv_v[wq][k], wv_i[wq][k]);
    float e0=1.f, e1=expf(v[1]-v[0]), e2=expf(v[2]-v[0]), e3=expf(v[3]-v[0]);
    float inv = 1.f/(e0+e1+e2+e3);
    s_idx[t][0]=ix[0]; s_idx[t][1]=ix[1]; s_idx[t][2]=ix[2]; s_idx[t][3]=ix[3];
    s_wgt[t][0]=e0*inv; s_wgt[t][1]=e1*inv; s_wgt[t][2]=e2*inv; s_wgt[t][3]=e3*inv;
  }
  __syncthreads();
  // ---- phase 3: e-chain (threads 0..255; others idle but join barriers) ----
  float c = (t < 256) ? ln_b_c[t] : 0.f;
  float cs = c, cq = c*c;
#pragma unroll
  for (int off=32; off; off>>=1){ cs += __shfl_xor(cs,off); cq += __shfl_xor(cq,off); }
  if (lane==0 && wv<4){ red[wv]=cs; red[8+wv]=cq; }
  __syncthreads();
  if (t < 256){
    float mean_c = (red[0]+red[1]+red[2]+red[3]) * (1.f/256.f);
    float var_c  = (red[8]+red[9]+red[10]+red[11]) * (1.f/256.f) - mean_c*mean_c;
    float cm = c - mean_c;
    float g = ln_g_e[t], be = ln_b_e[t];
    float a[4]; float q = 0.f;
#pragma unroll
    for (int k=0;k<4;k++){
      a[k] = 0.2f * (float)NCC * s_wgt[0][k];   // e_val[idxE_k] = a_k * ln_b_c
      if (s_idx[0][k] < 4) q += a[k];           // dv = mean(e_val[0..3])
    }
    q *= 0.25f;
    float se = 0.f;
#pragma unroll
    for (int k=0;k<4;k++){
      float tk = a[k] + 0.2f*q;
      se += tk*cm*rsqrtf(tk*tk*var_c + EPSL)*g + be;
    }
    float tz = 0.2f*q;
    se += (float)(NEE-4) * (tz*cm*rsqrtf(tz*tz*var_c + EPSL)*g + be);
    sumE[t] = se;
    if (t < 4){
      idxB2S[t] = s_idx[1][t]; wgtB2S[t] = s_wgt[1][t];
      idxComp[t] = s_idx[2][t]; wgtComp[t] = s_wgt[2][t];
    }
  }
}

// ---------------- KZ2: fused init -- counts/ncs/ncv init + W pack in one launch ----------------
// blocks [0,2048): ncs=0, ncv=base; [2048,2056): counts=0; [2056,2120): pack W.
__global__ __launch_bounds__(256) void kz2_init(int* __restrict__ counts,
    float* __restrict__ ncs, float* __restrict__ ncv,
    const float* __restrict__ ln_b_c, const float* __restrict__ sumE,
    const int* __restrict__ idxComp, const float* __restrict__ wgtComp,
    const float* __restrict__ W, ushort* __restrict__ Whi, ushort* __restrict__ Wlo)
{
  int bid = blockIdx.x;
  int t = threadIdx.x;
  if (bid < BATCH*NCC){
    int dest = bid & (NCC-1);
    float base = ln_b_c[t];
#pragma unroll
    for (int k=0;k<4;k++) if (dest == idxComp[k]) base = fmaf(0.2f*wgtComp[k], sumE[t], base);
    ncs[((size_t)bid<<8) + t] = 0.f;
    ncv[((size_t)bid<<8) + t] = base;
  } else if (bid < BATCH*NCC + 8){
    int i = (bid - BATCH*NCC)*256 + t;
    if (i < BATCH*NCC) counts[i] = 0;
  } else {
    int u = (bid - (BATCH*NCC + 8))*256 + t;   // 0..16383
    int kb = u >> 11;
    int cf = (u >> 6) & 31;
    int l  = u & 63;
    int k0 = kb*32 + ((l>>4)<<3);
    int col = (cf<<4) + (l&15);
    size_t off = (size_t)u << 3;
#pragma unroll
    for (int j=0;j<8;j++){
      float x = W[(size_t)(k0+j)*NCC + col];
      ushort h = f2bf(x);
      Whi[off+j] = h;
      Wlo[off+j] = f2bf(x - bf2f(h));
    }
  }
}

// ---------------- K1: window prop + tanh(tanh()) + LN(LN()+b2s rows) ----------------
__global__ __launch_bounds__(256) void k1_window(
    const float* __restrict__ s_state, const float* __restrict__ s_val,
    const float* __restrict__ w_pair_s, const float* __restrict__ ln_g_s, const float* __restrict__ ln_b_s,
    const float* __restrict__ sumE, const int* __restrict__ idxB2S, const float* __restrict__ wgtB2S,
    float* __restrict__ out_state, float* __restrict__ out_val)
{
  int gw = (blockIdx.x << 2) + (threadIdx.x >> 6);
  int lane = threadIdx.x & 63;
  int b = gw >> 13, r = gw & (SEQ-1);
  size_t rowoff = ((size_t)gw) << 8;
  size_t bbase = ((size_t)b) << 21;
  int d0 = lane << 2;
  float4 x = ld4(s_state + rowoff + d0);
  float4 v = ld4(s_val + rowoff + d0);
  float4 wp = ld4(w_pair_s + d0);
  float qx=x.x*wp.x, qy=x.y*wp.y, qz=x.z*wp.z, qw=x.w*wp.w;
  float sc[9]; float4 ns[9];
#pragma unroll
  for (int k=0;k<9;k++){
    int rr = r + k - 4;
    int rc = rr < 0 ? 0 : (rr > SEQ-1 ? SEQ-1 : rr);
    ns[k] = ld4(s_state + bbase + (((size_t)rc)<<8) + d0);
    sc[k] = qx*ns[k].x + qy*ns[k].y + qz*ns[k].z + qw*ns[k].w;
  }
#pragma unroll
  for (int off=32; off; off>>=1){
#pragma unroll
    for (int k=0;k<9;k++) sc[k] += __shfl_xor(sc[k], off);
  }
  float mx = -INFINITY;
#pragma unroll
  for (int k=0;k<9;k++){
    int rr = r + k - 4;
    sc[k] = (rr>=0 && rr<SEQ) ? sc[k]*INV_SQRT_D : -1e30f;
    mx = fmaxf(mx, sc[k]);
  }
  float ssum = 0.f;
#pragma unroll
  for (int k=0;k<9;k++){ sc[k] = __expf(sc[k]-mx); ssum += sc[k]; }
  float inv = __builtin_amdgcn_rcpf(ssum);
  float4 ds = make_float4(0,0,0,0), dv = make_float4(0,0,0,0);
#pragma unroll
  for (int k=0;k<9;k++) fma4(ds, sc[k]*inv, ns[k]);
#pragma unroll
  for (int k=0;k<9;k++){
    int rr = r + k - 4;
    int rc = rr < 0 ? 0 : (rr > SEQ-1 ? SEQ-1 : rr);
    float4 nv = ld4(s_val + bbase + (((size_t)rc)<<8) + d0);
    fma4(dv, sc[k]*inv, nv);
  }
  // state: tanh twice (step1 then step5 with ds==0)
  float4 s1, s2;
  s1.x = tanh_e2(x.x + 0.25f*ds.x); s1.y = tanh_e2(x.y + 0.25f*ds.y);
  s1.z = tanh_e2(x.z + 0.25f*ds.z); s1.w = tanh_e2(x.w + 0.25f*ds.w);
  s2.x = tanh_e2(s1.x); s2.y = tanh_e2(s1.y); s2.z = tanh_e2(s1.z); s2.w = tanh_e2(s1.w);
  st4(out_state + rowoff + d0, s2);
  // val: LN, +sparse rows, LN again
  float4 y;
  y.x = v.x + 0.25f*dv.x; y.y = v.y + 0.25f*dv.y; y.z = v.z + 0.25f*dv.z; y.w = v.w + 0.25f*dv.w;
  float sm = y.x+y.y+y.z+y.w;
  float sq = y.x*y.x+y.y*y.y+y.z*y.z+y.w*y.w;
#pragma unroll
  for (int off=32; off; off>>=1){ sm += __shfl_xor(sm,off); sq += __shfl_xor(sq,off); }
  float mean = sm*(1.f/256.f);
  float rstd = rsqrtf(sq*(1.f/256.f) - mean*mean + EPSL);
  float4 g = ld4(ln_g_s + d0), be = ld4(ln_b_s + d0);
  float4 y1;
  y1.x = (y.x-mean)*rstd*g.x + be.x; y1.y = (y.y-mean)*rstd*g.y + be.y;
  y1.z = (y.z-mean)*rstd*g.z + be.z; y1.w = (y.w-mean)*rstd*g.w + be.w;
#pragma unroll
  for (int k=0;k<4;k++){
    if (r == idxB2S[k]){
      float cb = 0.075f * wgtB2S[k];
      float4 sE = ld4(sumE + d0);
      fma4(y1, cb, sE);
    }
  }
  sm = y1.x+y1.y+y1.z+y1.w;
  sq = y1.x*y1.x+y1.y*y1.y+y1.z*y1.z+y1.w*y1.w;
#pragma unroll
  for (int off=32; off; off>>=1){ sm += __shfl_xor(sm,off); sq += __shfl_xor(sq,off); }
  float mean2 = sm*(1.f/256.f);
  float rstd2 = rsqrtf(sq*(1.f/256.f) - mean2*mean2 + EPSL);
  float4 o;
  o.x = (y1.x-mean2)*rstd2*g.x + be.x; o.y = (y1.y-mean2)*rstd2*g.y + be.y;
  o.z = (y1.z-mean2)*rstd2*g.z + be.z; o.w = (y1.w-mean2)*rstd2*g.w + be.w;
  st4(out_val + rowoff + d0, o);
}

// ---------------- K2: split-bf16 MFMA GEMM (32768x512x256) + per-row top4 ----------------
// R8 structure (32 rows/block, 4 blocks/CU, explicit pipeline) + s_setprio
// around each MFMA cluster (kb loop is barrier-free so waves drift out of
// phase -> scheduler has load-issuing vs MFMA-issuing waves to arbitrate).
__global__ __launch_bounds__(256, 4) void k2_mfma(
    const float* __restrict__ A, const ushort* __restrict__ Whi,
    const float* __restrict__ bias,
    int* __restrict__ topk_idx, float* __restrict__ topk_wgt, int* __restrict__ counts)
{
  __shared__ __align__(16) ushort Asp[2][32][264];   // [hi/lo][row][k], pad 264 -> 528B stride
  __shared__ float mv[32][17];                        // [row][w*4+r], stride 17 = conflict-free
  __shared__ int   mi[32][17];
  int tid = threadIdx.x;
  size_t row_base = (size_t)blockIdx.x * 32;
  int w = tid >> 6, l = tid & 63;
  int lg = l >> 4, lr = l & 15;
  // per-lane W base (shorts): w*4096 + l*8; lo plane at +131072 shorts
  const ushort* pw = Whi + ((w<<12) + (l<<3));

#define LOADG(KB, G, DST) { \
    const ushort* _p = pw + (KB)*16384 + (G)*1024; \
    DST[0] = *(const short8*)_p; \
    DST[2] = *(const short8*)(_p + 512); \
    DST[1] = *(const short8*)(_p + 131072); \
    DST[3] = *(const short8*)(_p + 131072 + 512); }

#define COMPG(G, B) { \
    __builtin_amdgcn_s_setprio(1); \
    int _c0 = (G)<<1, _c1 = _c0+1; \
    acc[0][_c0] = __builtin_amdgcn_mfma_f32_16x16x32_bf16(ah0, B[0], acc[0][_c0], 0,0,0); \
    acc[1][_c0] = __builtin_amdgcn_mfma_f32_16x16x32_bf16(ah1, B[0], acc[1][_c0], 0,0,0); \
    acc[0][_c1] = __builtin_amdgcn_mfma_f32_16x16x32_bf16(ah0, B[2], acc[0][_c1], 0,0,0); \
    acc[1][_c1] = __builtin_amdgcn_mfma_f32_16x16x32_bf16(ah1, B[2], acc[1][_c1], 0,0,0); \
    acc[0][_c0] = __builtin_amdgcn_mfma_f32_16x16x32_bf16(al0, B[0], acc[0][_c0], 0,0,0); \
    acc[1][_c0] = __builtin_amdgcn_mfma_f32_16x16x32_bf16(al1, B[0], acc[1][_c0], 0,0,0); \
    acc[0][_c0] = __builtin_amdgcn_mfma_f32_16x16x32_bf16(ah0, B[1], acc[0][_c0], 0,0,0); \
    acc[1][_c0] = __builtin_amdgcn_mfma_f32_16x16x32_bf16(ah1, B[1], acc[1][_c0], 0,0,0); \
    acc[0][_c1] = __builtin_amdgcn_mfma_f32_16x16x32_bf16(al0, B[2], acc[0][_c1], 0,0,0); \
    acc[1][_c1] = __builtin_amdgcn_mfma_f32_16x16x32_bf16(al1, B[2], acc[1][_c1], 0,0,0); \
    acc[0][_c1] = __builtin_amdgcn_mfma_f32_16x16x32_bf16(ah0, B[3], acc[0][_c1], 0,0,0); \
    acc[1][_c1] = __builtin_amdgcn_mfma_f32_16x16x32_bf16(ah1, B[3], acc[1][_c1], 0,0,0); \
    __builtin_amdgcn_s_setprio(0); }

  // prologue: first B group in flight before the A-stage barrier
  short8 bA[4], bB[4];
  LOADG(0, 0, bA);
  // ---- stage + split A (fp32 -> bf16 hi/lo) ----
  {
    const float4* Ab = (const float4*)(A + row_base*DD);
#pragma unroll
    for (int i=0;i<8;i++){
      int q = i*256 + tid;           // 0..2047 = 32 rows x 64 float4
      int row = q >> 6, k4 = q & 63;
      float4 x = Ab[q];
      ushort4 h, lo;
      h.x = f2bf(x.x); h.y = f2bf(x.y); h.z = f2bf(x.z); h.w = f2bf(x.w);
      lo.x = f2bf(x.x - bf2f(h.x)); lo.y = f2bf(x.y - bf2f(h.y));
      lo.z = f2bf(x.z - bf2f(h.z)); lo.w = f2bf(x.w - bf2f(h.w));
      *(ushort4*)&Asp[0][row][k4*4] = h;
      *(ushort4*)&Asp[1][row][k4*4] = lo;
    }
  }
  __syncthreads();
  f32x4 acc[2][8];
#pragma unroll
  for (int rf=0; rf<2; rf++)
#pragma unroll
    for (int cf=0; cf<8; cf++) acc[rf][cf] = (f32x4){0.f,0.f,0.f,0.f};
#pragma unroll 1
  for (int kb=0; kb<8; kb++){
    int ka = kb*32 + (lg<<3);
    short8 ah0 = *(const short8*)&Asp[0][lr][ka];
    short8 ah1 = *(const short8*)&Asp[0][16+lr][ka];
    short8 al0 = *(const short8*)&Asp[1][lr][ka];
    short8 al1 = *(const short8*)&Asp[1][16+lr][ka];
    LOADG(kb, 1, bB);
    __builtin_amdgcn_sched_barrier(0);
    COMPG(0, bA);
    LOADG(kb, 2, bA);
    __builtin_amdgcn_sched_barrier(0);
    COMPG(1, bB);
    LOADG(kb, 3, bB);
    __builtin_amdgcn_sched_barrier(0);
    COMPG(2, bA);
    if (kb < 7) LOADG(kb+1, 0, bA);
    __builtin_amdgcn_sched_barrier(0);
    COMPG(3, bB);
  }
#undef LOADG
#undef COMPG
  // ---- per-row top4 via 4 max-reduction rounds ----
  // D mapping: col = (w<<7)+(cf<<4)+lr, row = (rf<<4)+(lg<<2)+reg
  float bcol[8];
  int rel[8];
#pragma unroll
  for (int cf=0; cf<8; cf++){
    bcol[cf] = bias[(w<<7) + (cf<<4) + lr];
    rel[cf] = (cf<<4) + lr;
  }
#pragma unroll
  for (int rf=0; rf<2; rf++){
#pragma unroll
    for (int reg=0; reg<4; reg++){
      float av[8];
#pragma unroll
      for (int cf=0; cf<8; cf++) av[cf] = acc[rf][cf][reg] + bcol[cf];
      float tv4[4]; int tc4[4];
#pragma unroll
      for (int r=0; r<4; r++){
        float m = fmaxf(fmaxf(fmaxf(av[0],av[1]),fmaxf(av[2],av[3])),
                        fmaxf(fmaxf(av[4],av[5]),fmaxf(av[6],av[7])));
#pragma unroll
        for (int off=1; off<16; off<<=1) m = fmaxf(m, __shfl_xor(m, off));
        int cand = 0x7fffffff;
#pragma unroll
        for (int cf=7; cf>=0; cf--) cand = (av[cf]==m) ? rel[cf] : cand;  // lowest matching col in lane
#pragma unroll
        for (int off=1; off<16; off<<=1) cand = min(cand, __shfl_xor(cand, off));
        tv4[r] = m; tc4[r] = cand;
        if (r < 3){
#pragma unroll
          for (int cf=0; cf<8; cf++) av[cf] = (rel[cf]==cand) ? -INFINITY : av[cf];
        }
      }
      if (lr == 0){
        int rowl = (rf<<4) + (lg<<2) + reg;
#pragma unroll
        for (int r=0; r<4; r++){ mv[rowl][(w<<2)+r] = tv4[r]; mi[rowl][(w<<2)+r] = (w<<7) + tc4[r]; }
      }
    }
  }
  __syncthreads();
  if (tid < 32){
    float v[4]; int ix[4]; t4_init(v, ix);
#pragma unroll
    for (int j=0; j<16; j++) t4_insert(v, ix, mv[tid][j], mi[tid][j]);
    float e0=1.f, e1=expf(v[1]-v[0]), e2=expf(v[2]-v[0]), e3=expf(v[3]-v[0]);
    float inv = 1.f/(e0+e1+e2+e3);
    size_t row = row_base + tid;
    int b = (int)(row >> 13);
    topk_idx[row*4+0]=ix[0]; topk_idx[row*4+1]=ix[1]; topk_idx[row*4+2]=ix[2]; topk_idx[row*4+3]=ix[3];
    topk_wgt[row*4+0]=e0*inv; topk_wgt[row*4+1]=e1*inv; topk_wgt[row*4+2]=e2*inv; topk_wgt[row*4+3]=e3*inv;
    atomicAdd(&counts[(b<<9)+ix[0]],1); atomicAdd(&counts[(b<<9)+ix[1]],1);
    atomicAdd(&counts[(b<<9)+ix[2]],1); atomicAdd(&counts[(b<<9)+ix[3]],1);
  }
}

__global__ __launch_bounds__(256) void k3_scan(const int* __restrict__ counts,
    int* __restrict__ offsets, int* __restrict__ cursor)
{
  __shared__ int part[256];
  int t = threadIdx.x;
  int loc[8]; int s = 0;
#pragma unroll
  for (int i=0;i<8;i++){ loc[i] = counts[t*8+i]; s += loc[i]; }
  part[t] = s;
  __syncthreads();
  for (int off=1; off<256; off<<=1){
    int add = (t>=off)? part[t-off] : 0;
    __syncthreads();
    part[t] += add;
    __syncthreads();
  }
  int run = part[t] - s;
#pragma unroll
  for (int i=0;i<8;i++){ offsets[t*8+i] = run; cursor[t*8+i] = run; run += loc[i]; }
  if (t==255) offsets[BATCH*NCC] = run;
}

__global__ void k4_fill(const int* __restrict__ topk_idx, const float* __restrict__ topk_wgt,
    int* __restrict__ cursor, int* __restrict__ csr_src, float* __restrict__ csr_wgt)
{
  int row = blockIdx.x*256 + threadIdx.x;
  if (row >= BATCH*SEQ) return;
  int b = row >> 13, r = row & (SEQ-1);
#pragma unroll
  for (int k=0;k<4;k++){
    int dest = topk_idx[row*4+k];
    float wgt = topk_wgt[row*4+k];
    int pos = atomicAdd(&cursor[(b<<9)+dest], 1);
    csr_src[pos] = r;
    csr_wgt[pos] = 0.075f * wgt;   // fold sc_sb = ALPHA*BS2B*X_SC
  }
}

// ---------------- K5: per-destination gather-accumulate ----------------
__global__ __launch_bounds__(256) void k5_gather(
    const int* __restrict__ offsets, const int* __restrict__ csr_src, const float* __restrict__ csr_wgt,
    const float* __restrict__ st, const float* __restrict__ vl,
    float* __restrict__ ncs, float* __restrict__ ncv)
{
  int g2 = blockIdx.x;              // 0..4095
  int g  = g2 >> 1;                 // (b,dest)
  int half = g2 & 1;
  int b = g >> 9;
  int t = threadIdx.x;
  int i0 = offsets[g], i1 = offsets[g+1];
  int n = i1 - i0;
  int ia = i0 + ((n * half) >> 1);
  int ib = i0 + ((n * (half+1)) >> 1);
  if (ia >= ib) return;
  const float* Sb = st + (((size_t)b)<<21);
  const float* Vb = vl + (((size_t)b)<<21);
  float as0=0.f, as1=0.f, as2=0.f, as3=0.f;
  float av0=0.f, av1=0.f, av2=0.f, av3=0.f;
  int i = ia;
  for (; i+3 < ib; i += 4){
    int s0 = csr_src[i],   s1 = csr_src[i+1], s2 = csr_src[i+2], s3 = csr_src[i+3];
    float w0 = csr_wgt[i], w1 = csr_wgt[i+1], w2 = csr_wgt[i+2], w3 = csr_wgt[i+3];
    float x0 = Sb[((size_t)s0<<8)+t], y0 = Vb[((size_t)s0<<8)+t];
    float x1 = Sb[((size_t)s1<<8)+t], y1 = Vb[((size_t)s1<<8)+t];
    float x2 = Sb[((size_t)s2<<8)+t], y2 = Vb[((size_t)s2<<8)+t];
    float x3 = Sb[((size_t)s3<<8)+t], y3 = Vb[((size_t)s3<<8)+t];
    as0 = fmaf(w0,x0,as0); av0 = fmaf(w0,y0,av0);
    as1 = fmaf(w1,x1,as1); av1 = fmaf(w1,y1,av1);
    as2 = fmaf(w2,x2,as2); av2 = fmaf(w2,y2,av2);
    as3 = fmaf(w3,x3,as3); av3 = fmaf(w3,y3,av3);
  }
  for (; i < ib; i++){
    int src = csr_src[i];
    float wg = csr_wgt[i];
    as0 = fmaf(wg, Sb[((size_t)src<<8)+t], as0);
    av0 = fmaf(wg, Vb[((size_t)src<<8)+t], av0);
  }
  float accs = (as0+as1)+(as2+as3);
  float accv = (av0+av1)+(av2+av3);
  atomicAdd(&ncs[((size_t)g<<8) + t], accs);
  atomicAdd(&ncv[((size_t)g<<8) + t], accv);
}

// transpose nc_state (per batch 512x256 -> 256x512) for the score GEMM
__global__ __launch_bounds__(256) void k5t_transpose(const float* __restrict__ ncs, float* __restrict__ ncsT){
  __shared__ float tile[64][65];
  int b = blockIdx.z;
  int m0 = blockIdx.x*64, d0 = blockIdx.y*64;
  int tx = threadIdx.x & 63, ty = threadIdx.x >> 6;
  const float* src = ncs + (((size_t)b)<<17);
  for (int i=ty; i<64; i+=4) tile[i][tx] = src[(size_t)(m0+i)*DD + d0 + tx];
  __syncthreads();
  float* dst = ncsT + (((size_t)b)<<17);
  for (int i=ty; i<64; i+=4) dst[(size_t)(d0+i)*NCC + m0 + tx] = tile[tx][i];
}

// ---------------- K6: nc top-k prop (score GEMM + top4 + tanh/LN) ----------------
// 8 rows/block -> 256 blocks; kk loop staggered per block; fast transcendentals.
__global__ __launch_bounds__(256) void k6_ncprop(
    const float* __restrict__ ncs, const float* __restrict__ ncv, const float* __restrict__ ncsT,
    const float* __restrict__ w_pair_c, const float* __restrict__ ln_g_c, const float* __restrict__ ln_b_c,
    float* __restrict__ o_ncs, float* __restrict__ o_ncv)
{
  __shared__ float Alds[256*13];
  int tid = threadIdx.x;
  int b = blockIdx.x >> 6;
  int n_base = (blockIdx.x & 63) << 3;
  const float* Sb = ncs + (((size_t)b)<<17);
  const float* Vb = ncv + (((size_t)b)<<17);
  const float* Tb = ncsT + (((size_t)b)<<17);
  float wc = w_pair_c[tid] * INV_SQRT_D;
#pragma unroll
  for (int i=0;i<8;i++) Alds[tid*13 + i] = Sb[(size_t)(n_base+i)*DD + tid] * wc;
  __syncthreads();
  int lane = tid & 63, rg = tid >> 6;
  int r0 = rg << 1, c0 = lane << 3;
  float acc[2][8];
#pragma unroll
  for (int j=0;j<2;j++)
#pragma unroll
    for (int c=0;c<8;c++) acc[j][c] = 0.f;
  int kk0 = (blockIdx.x << 2) & 255;
  for (int i=0; i<256; i++){
    int kk = (kk0 + i) & 255;
    float4 w0 = ld4(Tb + (size_t)kk*NCC + c0);
    float4 w1 = ld4(Tb + (size_t)kk*NCC + c0 + 4);
    float a0 = Alds[kk*13 + r0];
    float a1 = Alds[kk*13 + r0 + 1];
    float wv_[8] = {w0.x,w0.y,w0.z,w0.w,w1.x,w1.y,w1.z,w1.w};
#pragma unroll
    for (int c=0;c<8;c++){
      acc[0][c] = fmaf(a0, wv_[c], acc[0][c]);
      acc[1][c] = fmaf(a1, wv_[c], acc[1][c]);
    }
  }
  int d0 = lane << 2;
  float4 g4 = ld4(ln_g_c + d0), be4 = ld4(ln_b_c + d0);
#pragma unroll
  for (int j=0;j<2;j++){
    float tv[4]; int ti[4]; t4_init(tv,ti);
#pragma unroll
    for (int c=0;c<8;c++) t4_insert(tv,ti, acc[j][c], c0+c);
    t4_wave_merge(tv,ti);
    float e0=1.f, e1=__expf(tv[1]-tv[0]), e2=__expf(tv[2]-tv[0]), e3=__expf(tv[3]-tv[0]);
    float inv = __builtin_amdgcn_rcpf(e0+e1+e2+e3);
    float aw[4] = {e0*inv, e1*inv, e2*inv, e3*inv};
    int n = n_base + r0 + j;
    float4 stt = ld4(Sb + (size_t)n*DD + d0);
    float4 vv  = ld4(Vb + (size_t)n*DD + d0);
    float4 dsv = make_float4(0,0,0,0), dvv = make_float4(0,0,0,0);
#pragma unroll
    for (int k=0;k<4;k++){
      float4 ms = ld4(Sb + (size_t)ti[k]*DD + d0);
      float4 mv = ld4(Vb + (size_t)ti[k]*DD + d0);
      fma4(dsv, aw[k], ms); fma4(dvv, aw[k], mv);
    }
    float4 os;
    os.x = tanh_e2(stt.x + 0.2f*dsv.x); os.y = tanh_e2(stt.y + 0.2f*dsv.y);
    os.z = tanh_e2(stt.z + 0.2f*dsv.z); os.w = tanh_e2(stt.w + 0.2f*dsv.w);
    size_t orow = (((size_t)b)<<17) + ((size_t)n<<8);
    st4(o_ncs + orow + d0, os);
    float4 y;
    y.x = vv.x + 0.2f*dvv.x; y.y = vv.y + 0.2f*dvv.y;
    y.z = vv.z + 0.2f*dvv.z; y.w = vv.w + 0.2f*dvv.w;
    float sm = y.x+y.y+y.z+y.w;
    float sq = y.x*y.x+y.y*y.y+y.z*y.z+y.w*y.w;
#pragma unroll
    for (int off=32; off; off>>=1){ sm += __shfl_xor(sm,off); sq += __shfl_xor(sq,off); }
    float mean = sm*(1.f/256.f);
    float rstd = rsqrtf(sq*(1.f/256.f) - mean*mean + EPSL);
    float4 o;
    o.x = (y.x-mean)*rstd*g4.x + be4.x; o.y = (y.y-mean)*rstd*g4.y + be4.y;
    o.z = (y.z-mean)*rstd*g4.z + be4.z; o.w = (y.w-mean)*rstd*g4.w + be4.w;
    st4(o_ncv + orow + d0, o);
  }
}

// ---------------- launch ----------------
extern "C" void kernel_launch(void* const* d_in, const int* in_sizes, int n_in,
                              void* d_out, int out_size, void* d_ws, size_t ws_size,
                              hipStream_t stream)
{
  const float* s_state = (const float*)d_in[0];
  const float* s_val   = (const float*)d_in[1];
  const float* w_pair_s= (const float*)d_in[2];
  const float* w_pair_c= (const float*)d_in[4];
  const float* b_expand= (const float*)d_in[6];
  const float* b_b2s   = (const float*)d_in[8];
  const float* b_comp  = (const float*)d_in[10];
  const float* W_s2b   = (const float*)d_in[11];
  const float* b_s2b   = (const float*)d_in[12];
  const float* ln_g_s  = (const float*)d_in[13];
  const float* ln_b_s  = (const float*)d_in[14];
  const float* ln_g_e  = (const float*)d_in[15];
  const float* ln_b_e  = (const float*)d_in[16];
  const float* ln_g_c  = (const float*)d_in[17];
  const float* ln_b_c  = (const float*)d_in[18];

  float* o_sstate = (float*)d_out;
  float* o_sval   = o_sstate + (size_t)BATCH*SEQ*DD;
  float* o_ncs    = o_sval + (size_t)BATCH*SEQ*DD;
  float* o_ncv    = o_ncs + (size_t)BATCH*NCC*DD;

  char* w = (char*)d_ws;
  float* sumE    = (float*)(w);
  int*   idxB2S  = (int*)(w + 1024);
  float* wgtB2S  = (float*)(w + 1040);
  int*   idxComp = (int*)(w + 1056);
  float* wgtComp = (float*)(w + 1072);
  int*   topk_idx= (int*)(w + 4096);
  float* topk_wgt= (float*)(w + 4096 + 524288);
  int*   counts  = (int*)(w + 1052672);
  int*   offsets = (int*)(w + 1069056);
  int*   cursor  = (int*)(w + 1085440);
  int*   csr_src = (int*)(w + 1101824);
  float* csr_wgt = (float*)(w + 1626112);
  float* ncs_ws  = (float*)(w + 2150400);
  float* ncv_ws  = ncs_ws + (size_t)BATCH*NCC*DD;
  float* ncsT_ws = ncv_ws + (size_t)BATCH*NCC*DD;
  ushort* wpk_hi = (ushort*)(w + 8441856);
  ushort* wpk_lo = (ushort*)(w + 8441856 + 262144);   // contiguous: lo = hi + 131072 shorts

  hipLaunchKernelGGL(k0_prep, dim3(1), dim3(1024), 0, stream,
      b_expand, b_b2s, b_comp, ln_b_c, ln_g_e, ln_b_e, sumE, idxB2S, wgtB2S, idxComp, wgtComp);
  hipLaunchKernelGGL(kz2_init, dim3(BATCH*NCC + 8 + 64), dim3(256), 0, stream,
      counts, ncs_ws, ncv_ws, ln_b_c, sumE, idxComp, wgtComp, W_s2b, wpk_hi, wpk_lo);
  hipLaunchKernelGGL(k1_window, dim3(8192), dim3(256), 0, stream,
      s_state, s_val, w_pair_s, ln_g_s, ln_b_s, sumE, idxB2S, wgtB2S, o_sstate, o_sval);
  hipLaunchKernelGGL(k2_mfma, dim3(1024), dim3(256), 0, stream,
      o_sstate, wpk_hi, b_s2b, topk_idx, topk_wgt, counts);
  hipLaunchKernelGGL(k3_scan, dim3(1), dim3(256), 0, stream, counts, offsets, cursor);
  hipLaunchKernelGGL(k4_fill, dim3(128), dim3(256), 0, stream,
      topk_idx, topk_wgt, cursor, csr_src, csr_wgt);
  hipLaunchKernelGGL(k5_gather, dim3(4096), dim3(256), 0, stream,
      offsets, csr_src, csr_wgt, o_sstate, o_sval, ncs_ws, ncv_ws);
  hipLaunchKernelGGL(k5t_transpose, dim3(8,4,BATCH), dim3(256), 0, stream, ncs_ws, ncsT_ws);
  hipLaunchKernelGGL(k6_ncprop, dim3(256), dim3(256), 0, stream,
      ncs_ws, ncv_ws, ncsT_ws, w_pair_c, ln_g_c, ln_b_c, o_ncs, o_ncv);
}